// Round 6
// baseline (871.672 us; speedup 1.0000x reference)
//
#include <hip/hip_runtime.h>
#include <cstdint>
#include <cstddef>

#define TT    100
#define MROWS 200      // T*C real rows
#define KDIM  16384    // H*W
#define DDIM  8192     // hypervector dim
#define KSL   16       // K slices (grid.z)
#define KPER  (KDIM / KSL)   // 1024

typedef __bf16 bf16x8 __attribute__((ext_vector_type(8)));
typedef float  f32x4  __attribute__((ext_vector_type(4)));

// ---------------------------------------------------------------------------
// Zero d_out (poisoned 0xAA before every timed launch).
// ---------------------------------------------------------------------------
__global__ __launch_bounds__(256) void zero_kernel(float* __restrict__ out) {
    out[blockIdx.x * 256 + threadIdx.x] = 0.f;
}

// ---------------------------------------------------------------------------
// Split 8 fp32 -> hi/lo bf16 planes, packed k-contiguous (2 shorts/dword).
// hi = round-half-up on mantissa bit 15 (<=0.5 ulp); lo = rn(v - hi), exact
// subtraction; recombined product exact to ~2^-16 relative.
// ---------------------------------------------------------------------------
static __device__ __forceinline__ void split_row(const float4 a, const float4 b,
                                                 uint4& hi, uint4& lo) {
    const float v[8] = {a.x, a.y, a.z, a.w, b.x, b.y, b.z, b.w};
    unsigned int h[8];
    unsigned int m[8];
#pragma unroll
    for (int i = 0; i < 8; ++i) {
        unsigned int u = __float_as_uint(v[i]);
        h[i] = (u + 0x8000u) & 0xFFFF0000u;            // rounded hi bits
        float l = v[i] - __uint_as_float(h[i]);        // exact
        m[i] = (__float_as_uint(l) + 0x8000u) & 0xFFFF0000u;
    }
    hi.x = (h[0] >> 16) | h[1];  hi.y = (h[2] >> 16) | h[3];
    hi.z = (h[4] >> 16) | h[5];  hi.w = (h[6] >> 16) | h[7];
    lo.x = (m[0] >> 16) | m[1];  lo.y = (m[2] >> 16) | m[3];
    lo.z = (m[4] >> 16) | m[5];  lo.w = (m[6] >> 16) | m[7];
}

// ---------------------------------------------------------------------------
// Fused GEMM + bind-reduce, 128x128x32 tile, register-double-buffered.
//   gesture[d] = sum_{m<200,k} hist[m,k] * pos[k,d] * time_w[m>>1,d] * pol_w[m&1,d]
// K-loop (m97 barrier-drain aware):
//   [barrier1; write packed regs->LDS; barrier2; ISSUE next loads;
//    frag reads interleaved with MFMA; convert next loads -> packed regs]
// NOTE: no min-waves __launch_bounds__ arg — round 5's (256,2) capped VGPRs
// at 128 and spilled the ~170 live regs of this structure to scratch inside
// the K-loop (kernels 253 -> 335 us). Let the allocator use up to 256.
// Zero d_ws usage (round-1 ws pipeline diverged on replay).
// ---------------------------------------------------------------------------
__global__ __launch_bounds__(256) void gemm_kernel(const float* __restrict__ hist,
                                                   const float* __restrict__ pos,
                                                   const float* __restrict__ time_w,
                                                   const float* __restrict__ pol_w,
                                                   float* __restrict__ out) {
    __shared__ alignas(16) unsigned short As[2][128][32];  // [plane][m][k] 16 KB
    __shared__ alignas(16) unsigned short Bs[128][40];     // [n][k], 80 B rows 10 KB
    __shared__ float sPart[128];

    const int t     = threadIdx.x;
    const int n0    = blockIdx.x * 128;
    const int m0    = blockIdx.y * 128;
    const int kbase = blockIdx.z * KPER;

    const int lane = t & 63;
    const int wv   = t >> 6;
    const int wm   = (wv & 1) * 64;    // wave m offset (2x2 wave grid)
    const int wn   = (wv >> 1) * 64;   // wave n offset
    const int l15  = lane & 15;
    const int q8   = (lane >> 4) * 8;  // k offset within fragment

    if (t < 128) sPart[t] = 0.f;       // visible after first __syncthreads

    // A staging: thread -> rows (ar, ar+64), 8 consecutive k.
    const int ar  = t >> 2;            // 0..63
    const int akb = (t & 3) * 8;       // 0,8,16,24
    const bool v0 = (m0 + ar)      < MROWS;
    const bool v1 = (m0 + ar + 64) < MROWS;
    const float* gA0 = hist + (size_t)(m0 + ar)      * KDIM + akb + kbase;
    const float* gA1 = hist + (size_t)(m0 + ar + 64) * KDIM + akb + kbase;

    // B staging: thread -> k-pair bp (rows 2bp,2bp+1) x n-quads {4bq, 64+4bq}.
    // Per-wave write banks: 2-way (free, m136); full 128-col coverage.
    const int bp = t & 15;             // k-pair 0..15
    const int bq = t >> 4;             // n-quad 0..15
    const float* gB0 = pos + ((size_t)kbase + 2 * bp)     * DDIM + n0 + 4 * bq;
    const float* gB1 = pos + ((size_t)kbase + 2 * bp + 1) * DDIM + n0 + 4 * bq;

    f32x4 acc[4][4];
#pragma unroll
    for (int s = 0; s < 4; ++s)
#pragma unroll
        for (int j = 0; j < 4; ++j) acc[s][j] = (f32x4){0.f, 0.f, 0.f, 0.f};

    // ---- prologue: load k=0, convert ----
    float4 a00 = {0,0,0,0}, a01 = {0,0,0,0}, a10 = {0,0,0,0}, a11 = {0,0,0,0};
    if (v0) { a00 = *(const float4*)(gA0);     a01 = *(const float4*)(gA0 + 4); }
    if (v1) { a10 = *(const float4*)(gA1);     a11 = *(const float4*)(gA1 + 4); }
    float4 bx0 = *(const float4*)(gB0);
    float4 bx1 = *(const float4*)(gB0 + 64);
    float4 by0 = *(const float4*)(gB1);
    float4 by1 = *(const float4*)(gB1 + 64);

    uint4 wAh0, wAl0, wAh1, wAl1;
    unsigned int wB[8];
    split_row(a00, a01, wAh0, wAl0);
    split_row(a10, a11, wAh1, wAl1);
    {
        const float x0[4] = {bx0.x, bx0.y, bx0.z, bx0.w};
        const float x1[4] = {bx1.x, bx1.y, bx1.z, bx1.w};
        const float y0[4] = {by0.x, by0.y, by0.z, by0.w};
        const float y1[4] = {by1.x, by1.y, by1.z, by1.w};
#pragma unroll
        for (int j = 0; j < 4; ++j) {
            wB[j]     = (__float_as_uint(x0[j]) >> 16) |
                        (__float_as_uint(y0[j]) & 0xFFFF0000u);   // exact: +/-1
            wB[4 + j] = (__float_as_uint(x1[j]) >> 16) |
                        (__float_as_uint(y1[j]) & 0xFFFF0000u);
        }
    }

    for (int kk = 0; kk < KPER; kk += 32) {
        __syncthreads();   // barrier1: previous frag reads done (no vmem pending)

        *(uint4*)&As[0][ar][akb]      = wAh0;
        *(uint4*)&As[1][ar][akb]      = wAl0;
        *(uint4*)&As[0][ar + 64][akb] = wAh1;
        *(uint4*)&As[1][ar + 64][akb] = wAl1;
#pragma unroll
        for (int j = 0; j < 4; ++j) {
            *(unsigned int*)&Bs[4 * bq + j][2 * bp]      = wB[j];
            *(unsigned int*)&Bs[64 + 4 * bq + j][2 * bp] = wB[4 + j];
        }

        __syncthreads();   // barrier2: tile visible (drains only LDS writes)

        // ---- issue prefetch for next k-step (in flight during MFMA) ----
        const int kn = (kk + 32 < KPER) ? kk + 32 : 0;   // wrap: harmless L2 hit
        a00 = (float4){0,0,0,0}; a01 = a00; a10 = a00; a11 = a00;
        if (v0) { a00 = *(const float4*)(gA0 + kn);     a01 = *(const float4*)(gA0 + kn + 4); }
        if (v1) { a10 = *(const float4*)(gA1 + kn);     a11 = *(const float4*)(gA1 + kn + 4); }
        bx0 = *(const float4*)(gB0 + (size_t)kn * DDIM);
        bx1 = *(const float4*)(gB0 + (size_t)kn * DDIM + 64);
        by0 = *(const float4*)(gB1 + (size_t)kn * DDIM);
        by1 = *(const float4*)(gB1 + (size_t)kn * DDIM + 64);

        // ---- fragments + MFMA, minimal liveness: fb (16 regs) + one fa
        //      pair (8 regs) at a time ----
        uint4 fb[4];
#pragma unroll
        for (int j = 0; j < 4; ++j)
            fb[j] = *(const uint4*)&Bs[wn + j * 16 + l15][q8];

#pragma unroll
        for (int s = 0; s < 4; ++s) {
            uint4 fa0 = *(const uint4*)&As[0][wm + s * 16 + l15][q8];
            uint4 fa1 = *(const uint4*)&As[1][wm + s * 16 + l15][q8];
#pragma unroll
            for (int j = 0; j < 4; ++j) {
                acc[s][j] = __builtin_amdgcn_mfma_f32_16x16x32_bf16(
                    __builtin_bit_cast(bf16x8, fa0),
                    __builtin_bit_cast(bf16x8, fb[j]), acc[s][j], 0, 0, 0);
                acc[s][j] = __builtin_amdgcn_mfma_f32_16x16x32_bf16(
                    __builtin_bit_cast(bf16x8, fa1),
                    __builtin_bit_cast(bf16x8, fb[j]), acc[s][j], 0, 0, 0);
            }
        }

        // ---- convert prefetched data (vmcnt waits here, a full MFMA phase
        //      after issue) ----
        split_row(a00, a01, wAh0, wAl0);
        split_row(a10, a11, wAh1, wAl1);
        {
            const float x0[4] = {bx0.x, bx0.y, bx0.z, bx0.w};
            const float x1[4] = {bx1.x, bx1.y, bx1.z, bx1.w};
            const float y0[4] = {by0.x, by0.y, by0.z, by0.w};
            const float y1[4] = {by1.x, by1.y, by1.z, by1.w};
#pragma unroll
            for (int j = 0; j < 4; ++j) {
                wB[j]     = (__float_as_uint(x0[j]) >> 16) |
                            (__float_as_uint(y0[j]) & 0xFFFF0000u);
                wB[4 + j] = (__float_as_uint(x1[j]) >> 16) |
                            (__float_as_uint(y1[j]) & 0xFFFF0000u);
            }
        }
    }

    // Epilogue: C/D layout col = lane&15, row = (lane>>4)*4 + reg (m89/m91).
    const int qrow = (lane >> 4) * 4;
#pragma unroll
    for (int j = 0; j < 4; ++j) {
        const int col = wn + j * 16 + l15;     // 0..127 within tile
        const int d   = n0 + col;
        const float p0 = pol_w[d];
        const float p1 = pol_w[DDIM + d];
        float part = 0.f;
#pragma unroll
        for (int s = 0; s < 4; ++s)
#pragma unroll
            for (int r = 0; r < 4; ++r) {
                const int m = m0 + wm + s * 16 + qrow + r;
                if (m < MROWS) {
                    const int tt_ = m >> 1;
                    const float w = time_w[(size_t)tt_ * DDIM + d] *
                                    ((m & 1) ? p1 : p0);
                    part += w * acc[s][j][r];
                }
            }
        atomicAdd(&sPart[col], part);
    }
    __syncthreads();
    if (t < 128) atomicAdd(out + n0 + t, sPart[t]);
}

// ---------------------------------------------------------------------------
// Final: out[d] = sign(out[d]) in place.
// ---------------------------------------------------------------------------
__global__ __launch_bounds__(256) void sign_kernel(float* __restrict__ out) {
    int d = blockIdx.x * 256 + threadIdx.x;
    float s = out[d];
    out[d] = (s > 0.f) ? 1.f : ((s < 0.f) ? -1.f : 0.f);
}

// ---------------------------------------------------------------------------
extern "C" void kernel_launch(void* const* d_in, const int* in_sizes, int n_in,
                              void* d_out, int out_size, void* d_ws, size_t ws_size,
                              hipStream_t stream) {
    const float* hist   = (const float*)d_in[0];   // [100,2,128,128]
    const float* time_w = (const float*)d_in[1];   // [100,8192]
    const float* pol_w  = (const float*)d_in[2];   // [2,8192]
    const float* pos_w  = (const float*)d_in[3];   // [16384,8192]
    float* out = (float*)d_out;                    // [8192]
    (void)d_ws; (void)ws_size;                     // zero workspace used

    zero_kernel<<<DDIM / 256, 256, 0, stream>>>(out);
    gemm_kernel<<<dim3(DDIM / 128, 2, KSL), 256, 0, stream>>>(hist, pos_w, time_w, pol_w, out);
    sign_kernel<<<DDIM / 256, 256, 0, stream>>>(out);
}

// Round 7
// 782.428 us; speedup vs baseline: 1.1141x; 1.1141x over previous
//
#include <hip/hip_runtime.h>
#include <cstdint>
#include <cstddef>

#define TT    100
#define MROWS 200      // T*C real rows
#define KDIM  16384    // H*W
#define DDIM  8192     // hypervector dim
#define KSL   16       // K slices (grid.z)
#define KPER  (KDIM / KSL)   // 1024

typedef __bf16 bf16x8 __attribute__((ext_vector_type(8)));
typedef float  f32x4  __attribute__((ext_vector_type(4)));

// ---------------------------------------------------------------------------
// Zero d_out (poisoned 0xAA before every timed launch).
// ---------------------------------------------------------------------------
__global__ __launch_bounds__(256) void zero_kernel(float* __restrict__ out) {
    out[blockIdx.x * 256 + threadIdx.x] = 0.f;
}

// ---------------------------------------------------------------------------
// Split 8 fp32 -> hi/lo bf16 planes, packed k-contiguous (2 shorts/dword).
// hi = round-half-up on mantissa bit 15 (<=0.5 ulp); lo = rn(v - hi), exact
// subtraction; recombined product exact to ~2^-16 relative. (absmax 0.0 in
// rounds 5/6.)
// ---------------------------------------------------------------------------
static __device__ __forceinline__ void split_row(const float4 a, const float4 b,
                                                 uint4& hi, uint4& lo) {
    const float v[8] = {a.x, a.y, a.z, a.w, b.x, b.y, b.z, b.w};
    unsigned int h[8];
    unsigned int m[8];
#pragma unroll
    for (int i = 0; i < 8; ++i) {
        unsigned int u = __float_as_uint(v[i]);
        h[i] = (u + 0x8000u) & 0xFFFF0000u;            // rounded hi bits
        float l = v[i] - __uint_as_float(h[i]);        // exact
        m[i] = (__float_as_uint(l) + 0x8000u) & 0xFFFF0000u;
    }
    hi.x = (h[0] >> 16) | h[1];  hi.y = (h[2] >> 16) | h[3];
    hi.z = (h[4] >> 16) | h[5];  hi.w = (h[6] >> 16) | h[7];
    lo.x = (m[0] >> 16) | m[1];  lo.y = (m[2] >> 16) | m[3];
    lo.z = (m[4] >> 16) | m[5];  lo.w = (m[6] >> 16) | m[7];
}

// ---------------------------------------------------------------------------
// Fused GEMM + bind-reduce, 128x128x32 tile, R3 skeleton (loads above
// barrier1 -> compiler cannot sink them past the barrier; latency hides in
// the barrier wait + other waves' MFMA). 512 threads = 8 waves of 32m x 64n:
// acc is 2x4 frags (32 regs/thread vs 64) -> ~2x the resident waves/CU of
// the 4-wave version. Rounds 5/6 taught: (a) never cap VGPRs below liveness
// (spill), (b) register-prefetch gets scheduler-sunk; occupancy is the
// reliable latency lever.
//   gesture[d] = sum_{m<200,k} hist[m,k] * pos[k,d] * time_w[m>>1,d] * pol_w[m&1,d]
// Zero d_ws usage (round-1 ws pipeline diverged on replay).
// ---------------------------------------------------------------------------
__global__ __launch_bounds__(512) void gemm_kernel(const float* __restrict__ hist,
                                                   const float* __restrict__ pos,
                                                   const float* __restrict__ time_w,
                                                   const float* __restrict__ pol_w,
                                                   float* __restrict__ out) {
    __shared__ alignas(16) unsigned short As[2][128][32];  // [plane][m][k] 16 KB
    __shared__ alignas(16) unsigned short Bs[128][40];     // [n][k], 80 B rows 10 KB
    __shared__ float sPart[128];

    const int t     = threadIdx.x;
    const int n0    = blockIdx.x * 128;
    const int m0    = blockIdx.y * 128;
    const int kbase = blockIdx.z * KPER;

    const int lane = t & 63;
    const int wv   = t >> 6;           // 0..7
    const int wm   = (wv & 3) * 32;    // wave m offset: 4 strips of 32
    const int wn   = (wv >> 2) * 64;   // wave n offset: 2 halves of 64
    const int l15  = lane & 15;
    const int q8   = (lane >> 4) * 8;  // k offset within fragment

    if (t < 128) sPart[t] = 0.f;       // visible after first __syncthreads

    // A staging: thread -> 1 row, 8 consecutive k. 512 thr cover 128x32.
    const int ar  = t >> 2;            // 0..127
    const int akb = (t & 3) * 8;       // 0,8,16,24
    const bool av = (m0 + ar) < MROWS;
    const float* gA = hist + (size_t)(m0 + ar) * KDIM + akb + kbase;

    // B staging: thread -> k-pair bp (rows 2bp,2bp+1) x n-quad bq.
    // 512 thr x 8 elems cover 128n x 32k exactly. Per-wave write banks:
    // bank = 16*(bq&1) + bp + 20j (mod 32) -> 2-way (free, m136).
    const int bp = t & 15;             // k-pair 0..15
    const int bq = t >> 4;             // n-quad 0..31
    const float* gB0 = pos + ((size_t)kbase + 2 * bp)     * DDIM + n0 + 4 * bq;
    const float* gB1 = pos + ((size_t)kbase + 2 * bp + 1) * DDIM + n0 + 4 * bq;

    f32x4 acc[2][4];
#pragma unroll
    for (int s = 0; s < 2; ++s)
#pragma unroll
        for (int j = 0; j < 4; ++j) acc[s][j] = (f32x4){0.f, 0.f, 0.f, 0.f};

    for (int kk = 0; kk < KPER; kk += 32) {
        // ---- loads at top: issued before barrier1, so they fly while this
        //      wave waits for stragglers' frag reads ----
        float4 a0 = {0,0,0,0}, a1 = {0,0,0,0};
        if (av) { a0 = *(const float4*)(gA + kk);  a1 = *(const float4*)(gA + kk + 4); }
        float4 bx = *(const float4*)(gB0 + (size_t)kk * DDIM);
        float4 by = *(const float4*)(gB1 + (size_t)kk * DDIM);

        __syncthreads();   // barrier1: previous frag reads done

        {   // convert + write A planes
            uint4 hi, lo;
            split_row(a0, a1, hi, lo);
            *(uint4*)&As[0][ar][akb] = hi;
            *(uint4*)&As[1][ar][akb] = lo;
        }
        {   // pack + write B (exact: pos is +/-1)
            const float xv[4] = {bx.x, bx.y, bx.z, bx.w};
            const float yv[4] = {by.x, by.y, by.z, by.w};
#pragma unroll
            for (int j = 0; j < 4; ++j) {
                unsigned int w = (__float_as_uint(xv[j]) >> 16) |
                                 (__float_as_uint(yv[j]) & 0xFFFF0000u);
                *(unsigned int*)&Bs[4 * bq + j][2 * bp] = w;
            }
        }

        __syncthreads();   // barrier2: tile visible

        // ---- fragments + MFMA ----
        uint4 fb[4];
#pragma unroll
        for (int j = 0; j < 4; ++j)
            fb[j] = *(const uint4*)&Bs[wn + j * 16 + l15][q8];

#pragma unroll
        for (int s = 0; s < 2; ++s) {
            uint4 fa0 = *(const uint4*)&As[0][wm + s * 16 + l15][q8];
            uint4 fa1 = *(const uint4*)&As[1][wm + s * 16 + l15][q8];
#pragma unroll
            for (int j = 0; j < 4; ++j) {
                acc[s][j] = __builtin_amdgcn_mfma_f32_16x16x32_bf16(
                    __builtin_bit_cast(bf16x8, fa0),
                    __builtin_bit_cast(bf16x8, fb[j]), acc[s][j], 0, 0, 0);
                acc[s][j] = __builtin_amdgcn_mfma_f32_16x16x32_bf16(
                    __builtin_bit_cast(bf16x8, fa1),
                    __builtin_bit_cast(bf16x8, fb[j]), acc[s][j], 0, 0, 0);
            }
        }
    }

    // Epilogue: C/D layout col = lane&15, row = (lane>>4)*4 + reg (m89/m91).
    const int qrow = (lane >> 4) * 4;
#pragma unroll
    for (int j = 0; j < 4; ++j) {
        const int col = wn + j * 16 + l15;     // 0..127 within tile
        const int d   = n0 + col;
        const float p0 = pol_w[d];
        const float p1 = pol_w[DDIM + d];
        float part = 0.f;
#pragma unroll
        for (int s = 0; s < 2; ++s)
#pragma unroll
            for (int r = 0; r < 4; ++r) {
                const int m = m0 + wm + s * 16 + qrow + r;
                if (m < MROWS) {
                    const int tt_ = m >> 1;
                    const float w = time_w[(size_t)tt_ * DDIM + d] *
                                    ((m & 1) ? p1 : p0);
                    part += w * acc[s][j][r];
                }
            }
        atomicAdd(&sPart[col], part);
    }
    __syncthreads();
    if (t < 128) atomicAdd(out + n0 + t, sPart[t]);
}

// ---------------------------------------------------------------------------
// Final: out[d] = sign(out[d]) in place.
// ---------------------------------------------------------------------------
__global__ __launch_bounds__(256) void sign_kernel(float* __restrict__ out) {
    int d = blockIdx.x * 256 + threadIdx.x;
    float s = out[d];
    out[d] = (s > 0.f) ? 1.f : ((s < 0.f) ? -1.f : 0.f);
}

// ---------------------------------------------------------------------------
extern "C" void kernel_launch(void* const* d_in, const int* in_sizes, int n_in,
                              void* d_out, int out_size, void* d_ws, size_t ws_size,
                              hipStream_t stream) {
    const float* hist   = (const float*)d_in[0];   // [100,2,128,128]
    const float* time_w = (const float*)d_in[1];   // [100,8192]
    const float* pol_w  = (const float*)d_in[2];   // [2,8192]
    const float* pos_w  = (const float*)d_in[3];   // [16384,8192]
    float* out = (float*)d_out;                    // [8192]
    (void)d_ws; (void)ws_size;                     // zero workspace used

    zero_kernel<<<DDIM / 256, 256, 0, stream>>>(out);
    gemm_kernel<<<dim3(DDIM / 128, 2, KSL), 512, 0, stream>>>(hist, pos_w, time_w, pol_w, out);
    sign_kernel<<<DDIM / 256, 256, 0, stream>>>(out);
}

// Round 8
// 772.735 us; speedup vs baseline: 1.1280x; 1.0125x over previous
//
#include <hip/hip_runtime.h>
#include <cstdint>
#include <cstddef>

#define TT    100
#define MROWS 200      // T*C real rows
#define KDIM  16384    // H*W
#define DDIM  8192     // hypervector dim
#define KSL   16       // K slices (grid.z)
#define KPER  (KDIM / KSL)   // 1024

typedef __bf16 bf16x8 __attribute__((ext_vector_type(8)));
typedef float  f32x4  __attribute__((ext_vector_type(4)));

// ---------------------------------------------------------------------------
// Zero d_out (poisoned 0xAA before every timed launch).
// ---------------------------------------------------------------------------
__global__ __launch_bounds__(256) void zero_kernel(float* __restrict__ out) {
    out[blockIdx.x * 256 + threadIdx.x] = 0.f;
}

// ---------------------------------------------------------------------------
// Split 8 fp32 -> hi/lo bf16 planes, packed k-contiguous (2 shorts/dword).
// hi = round-half-up on mantissa bit 15 (<=0.5 ulp); lo = rn(v - hi), exact
// subtraction; recombined product exact to ~2^-16 relative (absmax 0.0 R5-R7).
// ---------------------------------------------------------------------------
static __device__ __forceinline__ void split_row(const float4 a, const float4 b,
                                                 uint4& hi, uint4& lo) {
    const float v[8] = {a.x, a.y, a.z, a.w, b.x, b.y, b.z, b.w};
    unsigned int h[8];
    unsigned int m[8];
#pragma unroll
    for (int i = 0; i < 8; ++i) {
        unsigned int u = __float_as_uint(v[i]);
        h[i] = (u + 0x8000u) & 0xFFFF0000u;            // rounded hi bits
        float l = v[i] - __uint_as_float(h[i]);        // exact
        m[i] = (__float_as_uint(l) + 0x8000u) & 0xFFFF0000u;
    }
    hi.x = (h[0] >> 16) | h[1];  hi.y = (h[2] >> 16) | h[3];
    hi.z = (h[4] >> 16) | h[5];  hi.w = (h[6] >> 16) | h[7];
    lo.x = (m[0] >> 16) | m[1];  lo.y = (m[2] >> 16) | m[3];
    lo.z = (m[4] >> 16) | m[5];  lo.w = (m[6] >> 16) | m[7];
}

// ---------------------------------------------------------------------------
// Fused GEMM + bind-reduce, 128x128x32 tile, 512 thr (8 waves of 32m x 64n),
// CROSS-BARRIER software pipeline:
//   [barrier1; convert regs->LDS (loads issued last interval; vmcnt waited
//    here after ~a full k-step in flight); barrier2; issue loads for kk+32;
//    sched_barrier(0) pins them above the MFMA phase; frag reads + MFMA]
// Lessons encoded: R5 - never cap VGPRs below liveness (spill); R6 - issue
// and use in the SAME barrier interval gets scheduler-sunk (use must sit
// across a __syncthreads from the issue); R7 - occupancy alone isn't enough,
// per-wave MLP is the missing piece.
//   gesture[d] = sum_{m<200,k} hist[m,k] * pos[k,d] * time_w[m>>1,d] * pol_w[m&1,d]
// Zero d_ws usage (round-1 ws pipeline diverged on replay).
// ---------------------------------------------------------------------------
__global__ __launch_bounds__(512) void gemm_kernel(const float* __restrict__ hist,
                                                   const float* __restrict__ pos,
                                                   const float* __restrict__ time_w,
                                                   const float* __restrict__ pol_w,
                                                   float* __restrict__ out) {
    __shared__ alignas(16) unsigned short As[2][128][32];  // [plane][m][k] 16 KB
    __shared__ alignas(16) unsigned short Bs[128][40];     // [n][k], 80 B rows 10 KB
    __shared__ float sPart[128];

    const int t     = threadIdx.x;
    const int n0    = blockIdx.x * 128;
    const int m0    = blockIdx.y * 128;
    const int kbase = blockIdx.z * KPER;

    const int lane = t & 63;
    const int wv   = t >> 6;           // 0..7
    const int wm   = (wv & 3) * 32;    // wave m offset: 4 strips of 32
    const int wn   = (wv >> 2) * 64;   // wave n offset: 2 halves of 64
    const int l15  = lane & 15;
    const int q8   = (lane >> 4) * 8;  // k offset within fragment

    if (t < 128) sPart[t] = 0.f;       // visible after first __syncthreads

    // A staging: thread -> 1 row, 8 consecutive k. 512 thr cover 128x32.
    const int ar  = t >> 2;            // 0..127
    const int akb = (t & 3) * 8;       // 0,8,16,24
    const bool av = (m0 + ar) < MROWS;
    const float* gA = hist + (size_t)(m0 + ar) * KDIM + akb + kbase;

    // B staging: thread -> k-pair bp (rows 2bp,2bp+1) x n-quad bq.
    // 512 thr x 8 elems cover 128n x 32k exactly; 2-way write banks (free).
    const int bp = t & 15;             // k-pair 0..15
    const int bq = t >> 4;             // n-quad 0..31
    const float* gB0 = pos + ((size_t)kbase + 2 * bp)     * DDIM + n0 + 4 * bq;
    const float* gB1 = pos + ((size_t)kbase + 2 * bp + 1) * DDIM + n0 + 4 * bq;

    f32x4 acc[2][4];
#pragma unroll
    for (int s = 0; s < 2; ++s)
#pragma unroll
        for (int j = 0; j < 4; ++j) acc[s][j] = (f32x4){0.f, 0.f, 0.f, 0.f};

    // ---- prologue: issue loads for k-step 0. Invalid A rows keep zeros
    //      forever (never loaded), so padded As rows stay zero. ----
    float4 a0 = {0,0,0,0}, a1 = {0,0,0,0};
    if (av) { a0 = *(const float4*)(gA);  a1 = *(const float4*)(gA + 4); }
    float4 bx = *(const float4*)(gB0);
    float4 by = *(const float4*)(gB1);

    for (int kk = 0; kk < KPER; kk += 32) {
        __syncthreads();   // barrier1: previous frag reads done

        {   // convert + write A planes (vmcnt wait lands here; the load has
            // been in flight since the previous interval's issue point)
            uint4 hi, lo;
            split_row(a0, a1, hi, lo);
            *(uint4*)&As[0][ar][akb] = hi;
            *(uint4*)&As[1][ar][akb] = lo;
        }
        {   // pack + write B (exact: pos is +/-1)
            const float xv[4] = {bx.x, bx.y, bx.z, bx.w};
            const float yv[4] = {by.x, by.y, by.z, by.w};
#pragma unroll
            for (int j = 0; j < 4; ++j) {
                unsigned int w = (__float_as_uint(xv[j]) >> 16) |
                                 (__float_as_uint(yv[j]) & 0xFFFF0000u);
                *(unsigned int*)&Bs[4 * bq + j][2 * bp] = w;
            }
        }

        __syncthreads();   // barrier2: tile visible

        // ---- issue loads for the NEXT k-step. Their use (convert) is across
        //      barrier1 of the next iteration -> cannot be sunk to it. ----
        const int kn = (kk + 32 < KPER) ? kk + 32 : 0;   // wrap: harmless re-load
        if (av) { a0 = *(const float4*)(gA + kn);  a1 = *(const float4*)(gA + kn + 4); }
        bx = *(const float4*)(gB0 + (size_t)kn * DDIM);
        by = *(const float4*)(gB1 + (size_t)kn * DDIM);

        // Pin the issue point: nothing moves across this, so the loads stay
        // ABOVE the MFMA phase (one sched_barrier, not m141's full pinning).
        __builtin_amdgcn_sched_barrier(0);

        // ---- fragments + MFMA ----
        uint4 fb[4];
#pragma unroll
        for (int j = 0; j < 4; ++j)
            fb[j] = *(const uint4*)&Bs[wn + j * 16 + l15][q8];

#pragma unroll
        for (int s = 0; s < 2; ++s) {
            uint4 fa0 = *(const uint4*)&As[0][wm + s * 16 + l15][q8];
            uint4 fa1 = *(const uint4*)&As[1][wm + s * 16 + l15][q8];
#pragma unroll
            for (int j = 0; j < 4; ++j) {
                acc[s][j] = __builtin_amdgcn_mfma_f32_16x16x32_bf16(
                    __builtin_bit_cast(bf16x8, fa0),
                    __builtin_bit_cast(bf16x8, fb[j]), acc[s][j], 0, 0, 0);
                acc[s][j] = __builtin_amdgcn_mfma_f32_16x16x32_bf16(
                    __builtin_bit_cast(bf16x8, fa1),
                    __builtin_bit_cast(bf16x8, fb[j]), acc[s][j], 0, 0, 0);
            }
        }
    }

    // Epilogue: C/D layout col = lane&15, row = (lane>>4)*4 + reg (m89/m91).
    const int qrow = (lane >> 4) * 4;
#pragma unroll
    for (int j = 0; j < 4; ++j) {
        const int col = wn + j * 16 + l15;     // 0..127 within tile
        const int d   = n0 + col;
        const float p0 = pol_w[d];
        const float p1 = pol_w[DDIM + d];
        float part = 0.f;
#pragma unroll
        for (int s = 0; s < 2; ++s)
#pragma unroll
            for (int r = 0; r < 4; ++r) {
                const int m = m0 + wm + s * 16 + qrow + r;
                if (m < MROWS) {
                    const int tt_ = m >> 1;
                    const float w = time_w[(size_t)tt_ * DDIM + d] *
                                    ((m & 1) ? p1 : p0);
                    part += w * acc[s][j][r];
                }
            }
        atomicAdd(&sPart[col], part);
    }
    __syncthreads();
    if (t < 128) atomicAdd(out + n0 + t, sPart[t]);
}

// ---------------------------------------------------------------------------
// Final: out[d] = sign(out[d]) in place.
// ---------------------------------------------------------------------------
__global__ __launch_bounds__(256) void sign_kernel(float* __restrict__ out) {
    int d = blockIdx.x * 256 + threadIdx.x;
    float s = out[d];
    out[d] = (s > 0.f) ? 1.f : ((s < 0.f) ? -1.f : 0.f);
}

// ---------------------------------------------------------------------------
extern "C" void kernel_launch(void* const* d_in, const int* in_sizes, int n_in,
                              void* d_out, int out_size, void* d_ws, size_t ws_size,
                              hipStream_t stream) {
    const float* hist   = (const float*)d_in[0];   // [100,2,128,128]
    const float* time_w = (const float*)d_in[1];   // [100,8192]
    const float* pol_w  = (const float*)d_in[2];   // [2,8192]
    const float* pos_w  = (const float*)d_in[3];   // [16384,8192]
    float* out = (float*)d_out;                    // [8192]
    (void)d_ws; (void)ws_size;                     // zero workspace used

    zero_kernel<<<DDIM / 256, 256, 0, stream>>>(out);
    gemm_kernel<<<dim3(DDIM / 128, 2, KSL), 512, 0, stream>>>(hist, pos_w, time_w, pol_w, out);
    sign_kernel<<<DDIM / 256, 256, 0, stream>>>(out);
}